// Round 1
// baseline (1038.319 us; speedup 1.0000x reference)
//
#include <hip/hip_runtime.h>
#include <math.h>

#define NN 100000

// ---------------- workspace layout (bytes) ----------------
// 0        : int flag (edge_index dtype: 1 = int64, 0 = int32)
// 256      : float  dinv[NN]      (holds deg first, then deg^-1/2)
// 400256   : float4 xs[NN]        (x * dinv, padded to 16B)
// 2000256  : float4 agg1[NN]      (layer-1 scatter accumulator)
// 3600256  : float2 hs2[NN]       ((relu(L1)@W2) * dinv)
// 4400256  : float2 agg2[NN]      (layer-2 scatter accumulator)

__global__ void k_detect(const void* ei, int* flag) {
    if (blockIdx.x == 0 && threadIdx.x == 0) {
        const long long* p = (const long long*)ei;
        int ok = 1;
        for (int i = 0; i < 64; ++i) {
            long long v = p[i];
            if (v < 0 || v >= NN) { ok = 0; break; }
        }
        *flag = ok;
    }
}

__global__ void k_init(float* deg, float4* agg1, float2* agg2) {
    int i = blockIdx.x * blockDim.x + threadIdx.x;
    if (i < NN) {
        deg[i]  = 1.0f;                      // self-loop contribution
        agg1[i] = make_float4(0.f, 0.f, 0.f, 0.f);
        agg2[i] = make_float2(0.f, 0.f);
    }
}

template <typename T>
__device__ __forceinline__ void deg_loop(const T* col, long long E, float* deg) {
    long long stride = (long long)gridDim.x * blockDim.x;
    for (long long e = (long long)blockIdx.x * blockDim.x + threadIdx.x; e < E; e += stride)
        atomicAdd(&deg[(int)col[e]], 1.0f);
}

__global__ void k_deg(const void* ei, long long E, const int* flag, float* deg) {
    if (*flag) deg_loop(((const long long*)ei) + E, E, deg);
    else       deg_loop(((const int*)ei) + E, E, deg);
}

__global__ void k_prep(const float* __restrict__ x, float* dinv, float4* xs) {
    int i = blockIdx.x * blockDim.x + threadIdx.x;
    if (i < NN) {
        float d = rsqrtf(dinv[i]);   // dinv[] currently holds deg (>=1 always)
        dinv[i] = d;
        xs[i] = make_float4(x[3*i] * d, x[3*i+1] * d, x[3*i+2] * d, 0.f);
    }
}

template <typename T>
__device__ __forceinline__ void sc1_loop(const T* ei, long long E,
                                         const float4* __restrict__ xs, float4* agg1) {
    long long stride = (long long)gridDim.x * blockDim.x;
    for (long long e = (long long)blockIdx.x * blockDim.x + threadIdx.x; e < E; e += stride) {
        int r = (int)ei[e];
        int c = (int)ei[E + e];
        float4 v = xs[r];
        atomicAdd(&agg1[c].x, v.x);
        atomicAdd(&agg1[c].y, v.y);
        atomicAdd(&agg1[c].z, v.z);
    }
}

__global__ void k_scatter1(const void* ei, long long E, const int* flag,
                           const float4* __restrict__ xs, float4* agg1) {
    if (*flag) sc1_loop((const long long*)ei, E, xs, agg1);
    else       sc1_loop((const int*)ei, E, xs, agg1);
}

__global__ void k_layer(const float* __restrict__ W1, const float* __restrict__ b1,
                        const float* __restrict__ W2, const float* __restrict__ b2,
                        const float* __restrict__ dinv, const float4* __restrict__ xs,
                        const float4* __restrict__ agg1, float2* hs2) {
    int i = blockIdx.x * blockDim.x + threadIdx.x;
    if (i >= NN) return;
    float d  = dinv[i];
    float4 a = agg1[i];
    float4 s = xs[i];
    // layer-1 pre-activation input vector (3-dim), fully normalized
    float t0 = d * (a.x + s.x);
    float t1 = d * (a.y + s.y);
    float t2 = d * (a.z + s.z);
    float g0 = 0.f, g1 = 0.f;
#pragma unroll
    for (int j = 0; j < 16; ++j) {
        float h = fmaxf(t0 * W1[j] + t1 * W1[16 + j] + t2 * W1[32 + j] + b1[j], 0.f);
        g0 += h * W2[2*j];
        g1 += h * W2[2*j + 1];
    }
    hs2[i] = make_float2(g0 * d, g1 * d);
}

template <typename T>
__device__ __forceinline__ void sc2_loop(const T* ei, long long E,
                                         const float2* __restrict__ hs2, float2* agg2) {
    long long stride = (long long)gridDim.x * blockDim.x;
    for (long long e = (long long)blockIdx.x * blockDim.x + threadIdx.x; e < E; e += stride) {
        int r = (int)ei[e];
        int c = (int)ei[E + e];
        float2 v = hs2[r];
        atomicAdd(&agg2[c].x, v.x);
        atomicAdd(&agg2[c].y, v.y);
    }
}

__global__ void k_scatter2(const void* ei, long long E, const int* flag,
                           const float2* __restrict__ hs2, float2* agg2) {
    if (*flag) sc2_loop((const long long*)ei, E, hs2, agg2);
    else       sc2_loop((const int*)ei, E, hs2, agg2);
}

__global__ void k_out(const float* __restrict__ b2, const float* __restrict__ dinv,
                      const float2* __restrict__ hs2, const float2* __restrict__ agg2,
                      float2* out) {
    int i = blockIdx.x * blockDim.x + threadIdx.x;
    if (i >= NN) return;
    float d  = dinv[i];
    float2 a = agg2[i];
    float2 s = hs2[i];
    float z0 = d * (a.x + s.x) + b2[0];
    float z1 = d * (a.y + s.y) + b2[1];
    float m  = fmaxf(z0, z1);
    float l  = m + logf(expf(z0 - m) + expf(z1 - m));
    out[i] = make_float2(z0 - l, z1 - l);
}

extern "C" void kernel_launch(void* const* d_in, const int* in_sizes, int n_in,
                              void* d_out, int out_size, void* d_ws, size_t ws_size,
                              hipStream_t stream) {
    const float* x  = (const float*)d_in[0];
    const void*  ei = d_in[1];
    const float* W1 = (const float*)d_in[2];
    const float* b1 = (const float*)d_in[3];
    const float* W2 = (const float*)d_in[4];
    const float* b2 = (const float*)d_in[5];
    long long E = (long long)in_sizes[1] / 2;

    char* ws = (char*)d_ws;
    int*    flag = (int*)ws;
    float*  dinv = (float*)(ws + 256);
    float4* xs   = (float4*)(ws + 400256);
    float4* agg1 = (float4*)(ws + 2000256);
    float2* hs2  = (float2*)(ws + 3600256);
    float2* agg2 = (float2*)(ws + 4400256);
    float2* out  = (float2*)d_out;

    int ngrid = (NN + 255) / 256;
    int egrid = (int)((E + 255) / 256);
    if (egrid > 12800) egrid = 12800;

    k_detect  <<<1, 64, 0, stream>>>(ei, flag);
    k_init    <<<ngrid, 256, 0, stream>>>(dinv, agg1, agg2);
    k_deg     <<<egrid, 256, 0, stream>>>(ei, E, flag, dinv);
    k_prep    <<<ngrid, 256, 0, stream>>>(x, dinv, xs);
    k_scatter1<<<egrid, 256, 0, stream>>>(ei, E, flag, xs, agg1);
    k_layer   <<<ngrid, 256, 0, stream>>>(W1, b1, W2, b2, dinv, xs, agg1, hs2);
    k_scatter2<<<egrid, 256, 0, stream>>>(ei, E, flag, hs2, agg2);
    k_out     <<<ngrid, 256, 0, stream>>>(b2, dinv, hs2, agg2, out);
}

// Round 2
// 1029.857 us; speedup vs baseline: 1.0082x; 1.0082x over previous
//
#include <hip/hip_runtime.h>
#include <math.h>

#define NN 100000
#define NX 8   // XCDs on MI355X (measured: learn_hip m09)

// ---------------- workspace layout (bytes) ----------------
// 0        : int flag (edge_index dtype: 1 = int64, 0 = int32)
// 256      : float  dinv[NN]
// 400256   : float4 xs[NN]        (x * dinv)
// 2000256  : float2 hs2[NN]       ((relu(L1)@W2) * dinv)
// 2800256  : float  degR[nrep][NN]
//  then    : float4 agg1R[nrep][NN]
//  then    : float2 agg2R[nrep][NN]

__device__ __forceinline__ int xcc_id() {
    int x;
    asm volatile("s_getreg_b32 %0, hwreg(HW_REG_XCC_ID)" : "=s"(x));
    return x & (NX - 1);
}

// local=1: RMW executes in this XCD's TCC (L2-resident, no sc1 bypass).
// Safe because each replica is only ever touched by waves on its own XCD.
__device__ __forceinline__ void atom_add(float* p, float v, int local) {
    if (local) __hip_atomic_fetch_add(p, v, __ATOMIC_RELAXED, __HIP_MEMORY_SCOPE_WORKGROUP);
    else       atomicAdd(p, v);
}

__global__ void k_detect(const void* ei, int* flag) {
    if (blockIdx.x == 0 && threadIdx.x == 0) {
        const long long* p = (const long long*)ei;
        int ok = 1;
        for (int i = 0; i < 64; ++i) {
            long long v = p[i];
            if (v < 0 || v >= NN) { ok = 0; break; }
        }
        *flag = ok;
    }
}

__global__ void k_zero(float4* z, long long n4) {
    long long stride = (long long)gridDim.x * blockDim.x;
    for (long long i = (long long)blockIdx.x * blockDim.x + threadIdx.x; i < n4; i += stride)
        z[i] = make_float4(0.f, 0.f, 0.f, 0.f);
}

template <typename T>
__device__ __forceinline__ void deg_loop(const T* col, long long E, float* deg, int local) {
    long long stride = (long long)gridDim.x * blockDim.x;
    for (long long e = (long long)blockIdx.x * blockDim.x + threadIdx.x; e < E; e += stride)
        atom_add(&deg[(int)col[e]], 1.0f, local);
}

__global__ void k_deg(const void* ei, long long E, const int* flag, float* degR, int nrep) {
    float* deg = degR + (size_t)(nrep > 1 ? xcc_id() : 0) * NN;
    if (*flag) deg_loop(((const long long*)ei) + E, E, deg, nrep > 1);
    else       deg_loop(((const int*)ei) + E, E, deg, nrep > 1);
}

__global__ void k_prep(const float* __restrict__ x, const float* __restrict__ degR,
                       int nrep, float* dinv, float4* xs) {
    int i = blockIdx.x * blockDim.x + threadIdx.x;
    if (i >= NN) return;
    float s = 1.0f;                          // self-loop
    for (int k = 0; k < nrep; ++k) s += degR[(size_t)k * NN + i];
    float d = rsqrtf(s);
    dinv[i] = d;
    xs[i] = make_float4(x[3*i] * d, x[3*i+1] * d, x[3*i+2] * d, 0.f);
}

template <typename T>
__device__ __forceinline__ void sc1_loop(const T* ei, long long E,
                                         const float4* __restrict__ xs, float4* agg1, int local) {
    long long stride = (long long)gridDim.x * blockDim.x;
    for (long long e = (long long)blockIdx.x * blockDim.x + threadIdx.x; e < E; e += stride) {
        int r = (int)ei[e];
        int c = (int)ei[E + e];
        float4 v = xs[r];
        atom_add(&agg1[c].x, v.x, local);
        atom_add(&agg1[c].y, v.y, local);
        atom_add(&agg1[c].z, v.z, local);
    }
}

__global__ void k_scatter1(const void* ei, long long E, const int* flag,
                           const float4* __restrict__ xs, float4* agg1R, int nrep) {
    float4* agg1 = agg1R + (size_t)(nrep > 1 ? xcc_id() : 0) * NN;
    if (*flag) sc1_loop((const long long*)ei, E, xs, agg1, nrep > 1);
    else       sc1_loop((const int*)ei, E, xs, agg1, nrep > 1);
}

__global__ void k_layer(const float* __restrict__ W1, const float* __restrict__ b1,
                        const float* __restrict__ W2, const float* __restrict__ b2,
                        const float* __restrict__ dinv, const float4* __restrict__ xs,
                        const float4* __restrict__ agg1R, int nrep, float2* hs2) {
    int i = blockIdx.x * blockDim.x + threadIdx.x;
    if (i >= NN) return;
    float d  = dinv[i];
    float4 s = xs[i];
    float a0 = s.x, a1 = s.y, a2 = s.z;
    for (int k = 0; k < nrep; ++k) {
        float4 a = agg1R[(size_t)k * NN + i];
        a0 += a.x; a1 += a.y; a2 += a.z;
    }
    float t0 = d * a0, t1 = d * a1, t2 = d * a2;
    float g0 = 0.f, g1 = 0.f;
#pragma unroll
    for (int j = 0; j < 16; ++j) {
        float h = fmaxf(t0 * W1[j] + t1 * W1[16 + j] + t2 * W1[32 + j] + b1[j], 0.f);
        g0 += h * W2[2*j];
        g1 += h * W2[2*j + 1];
    }
    hs2[i] = make_float2(g0 * d, g1 * d);
}

template <typename T>
__device__ __forceinline__ void sc2_loop(const T* ei, long long E,
                                         const float2* __restrict__ hs2, float2* agg2, int local) {
    long long stride = (long long)gridDim.x * blockDim.x;
    for (long long e = (long long)blockIdx.x * blockDim.x + threadIdx.x; e < E; e += stride) {
        int r = (int)ei[e];
        int c = (int)ei[E + e];
        float2 v = hs2[r];
        atom_add(&agg2[c].x, v.x, local);
        atom_add(&agg2[c].y, v.y, local);
    }
}

__global__ void k_scatter2(const void* ei, long long E, const int* flag,
                           const float2* __restrict__ hs2, float2* agg2R, int nrep) {
    float2* agg2 = agg2R + (size_t)(nrep > 1 ? xcc_id() : 0) * NN;
    if (*flag) sc2_loop((const long long*)ei, E, hs2, agg2, nrep > 1);
    else       sc2_loop((const int*)ei, E, hs2, agg2, nrep > 1);
}

__global__ void k_out(const float* __restrict__ b2, const float* __restrict__ dinv,
                      const float2* __restrict__ hs2, const float2* __restrict__ agg2R,
                      int nrep, float2* out) {
    int i = blockIdx.x * blockDim.x + threadIdx.x;
    if (i >= NN) return;
    float d  = dinv[i];
    float2 s = hs2[i];
    float a0 = s.x, a1 = s.y;
    for (int k = 0; k < nrep; ++k) {
        float2 a = agg2R[(size_t)k * NN + i];
        a0 += a.x; a1 += a.y;
    }
    float z0 = d * a0 + b2[0];
    float z1 = d * a1 + b2[1];
    float m  = fmaxf(z0, z1);
    float l  = m + logf(expf(z0 - m) + expf(z1 - m));
    out[i] = make_float2(z0 - l, z1 - l);
}

extern "C" void kernel_launch(void* const* d_in, const int* in_sizes, int n_in,
                              void* d_out, int out_size, void* d_ws, size_t ws_size,
                              hipStream_t stream) {
    const float* x  = (const float*)d_in[0];
    const void*  ei = d_in[1];
    const float* W1 = (const float*)d_in[2];
    const float* b1 = (const float*)d_in[3];
    const float* W2 = (const float*)d_in[4];
    const float* b2 = (const float*)d_in[5];
    long long E = (long long)in_sizes[1] / 2;

    // per-XCD replicas need ~25.2 MB of ws; fall back to single replica otherwise
    const size_t per_rep = 400000 + 1600000 + 800000;          // deg + agg1 + agg2
    int nrep = (ws_size >= 2800256 + (size_t)NX * per_rep) ? NX : 1;

    char* ws = (char*)d_ws;
    int*    flag = (int*)ws;
    float*  dinv = (float*)(ws + 256);
    float4* xs   = (float4*)(ws + 400256);
    float2* hs2  = (float2*)(ws + 2000256);
    size_t o = 2800256;
    float*  degR  = (float*) (ws + o); o += (size_t)nrep * 400000;
    float4* agg1R = (float4*)(ws + o); o += (size_t)nrep * 1600000;
    float2* agg2R = (float2*)(ws + o);
    float2* out   = (float2*)d_out;

    int ngrid = (NN + 255) / 256;
    int egrid = (int)((E + 255) / 256);
    if (egrid > 12800) egrid = 12800;
    long long n4 = (long long)nrep * per_rep / 16;
    int zgrid = (int)((n4 + 255) / 256);
    if (zgrid > 2048) zgrid = 2048;

    k_detect  <<<1, 64, 0, stream>>>(ei, flag);
    k_zero    <<<zgrid, 256, 0, stream>>>((float4*)(ws + 2800256), n4);
    k_deg     <<<egrid, 256, 0, stream>>>(ei, E, flag, degR, nrep);
    k_prep    <<<ngrid, 256, 0, stream>>>(x, degR, nrep, dinv, xs);
    k_scatter1<<<egrid, 256, 0, stream>>>(ei, E, flag, xs, agg1R, nrep);
    k_layer   <<<ngrid, 256, 0, stream>>>(W1, b1, W2, b2, dinv, xs, agg1R, nrep, hs2);
    k_scatter2<<<egrid, 256, 0, stream>>>(ei, E, flag, hs2, agg2R, nrep);
    k_out     <<<ngrid, 256, 0, stream>>>(b2, dinv, hs2, agg2R, nrep, out);
}

// Round 4
// 425.087 us; speedup vs baseline: 2.4426x; 2.4227x over previous
//
#include <hip/hip_runtime.h>
#include <math.h>

#define NN 100000
#define CHUNK 1024
#define NCHUNK 98          // ceil(NN/1024)
#define NX 8               // XCDs (measured: learn_hip m09)

// ---------------- ws layout (bytes) ----------------
#define O_FLAG  0
#define O_CNT   256
#define O_OFF   400256
#define O_CUR   800256
#define O_DINV  1200256
#define O_CSUM  1600256
#define O_CBASE 1601280
#define O_XS    1602560
#define O_HS2   3202560
#define O_RIDX  4002560            // u32[E] -> 12.8 MB
#define O_R     16802560           // u16[E] -> 6.4 MB (full path only)
#define O_CNTL  23202560           // u32[NX][NN] (A/B timing probe)
#define SZ_FULL_AB 26402560
#define SZ_FULL    23202560
#define SZ_MID     16802560
// low path (R1 scatter design):
#define L_DINV  256
#define L_XS    400256
#define L_HS2   2000256
#define L_AGG1  2800256
#define L_AGG2  4400256

__device__ __forceinline__ int xcc_id() {
    int x;
    asm volatile("s_getreg_b32 %0, hwreg(HW_REG_XCC_ID)" : "=s"(x));
    return x & (NX - 1);
}

// no sc flags -> RMW should execute in the issuing XCD's own TCC (timing probe only)
__device__ __forceinline__ void atom_add_local_u32(unsigned* p, unsigned v) {
    asm volatile("global_atomic_add %0, %1, off" :: "v"(p), "v"(v) : "memory");
}

__global__ void k_detect(const void* ei, int* flag) {
    if (blockIdx.x == 0 && threadIdx.x == 0) {
        const long long* p = (const long long*)ei;
        int ok = 1;
        for (int i = 0; i < 64; ++i) {
            long long v = p[i];
            if (v < 0 || v >= NN) { ok = 0; break; }
        }
        *flag = ok;
    }
}

__global__ void k_zero(float4* z, long long n4) {
    long long stride = (long long)gridDim.x * blockDim.x;
    for (long long i = (long long)blockIdx.x * blockDim.x + threadIdx.x; i < n4; i += stride)
        z[i] = make_float4(0.f, 0.f, 0.f, 0.f);
}

// ---------------- full path: single atomic pass (rank) ----------------
template <typename T>
__device__ __forceinline__ void rank_loop(const T* __restrict__ col, long long E,
                                          unsigned* __restrict__ cnt,
                                          unsigned short* __restrict__ r) {
    long long stride = (long long)gridDim.x * blockDim.x;
    for (long long e = (long long)blockIdx.x * blockDim.x + threadIdx.x; e < E; e += stride)
        r[e] = (unsigned short)atomicAdd(&cnt[(unsigned)col[e]], 1u);
}
__global__ void k_rank(const void* ei, long long E, const int* flag,
                       unsigned* cnt, unsigned short* r) {
    if (*flag) rank_loop(((const long long*)ei) + E, E, cnt, r);
    else       rank_loop(((const int*)ei) + E, E, cnt, r);
}

__global__ void k_scan1(const unsigned* __restrict__ cnt, unsigned* __restrict__ off,
                        unsigned* __restrict__ csum) {
    __shared__ unsigned lds[256];
    int t = threadIdx.x;
    int base = blockIdx.x * CHUNK + t * 4;
    unsigned v[4];
#pragma unroll
    for (int k = 0; k < 4; ++k) { int i = base + k; v[k] = (i < NN) ? cnt[i] : 0u; }
    unsigned s = v[0] + v[1] + v[2] + v[3];
    lds[t] = s; __syncthreads();
    for (int o = 1; o < 256; o <<= 1) {
        unsigned add = (t >= o) ? lds[t - o] : 0u; __syncthreads();
        lds[t] += add; __syncthreads();
    }
    unsigned excl = lds[t] - s;
    if (t == 255) csum[blockIdx.x] = lds[255];
#pragma unroll
    for (int k = 0; k < 4; ++k) { int i = base + k; if (i < NN) off[i] = excl; excl += v[k]; }
}

__global__ void k_scan2(unsigned* __restrict__ csum, unsigned* __restrict__ cbase) {
    __shared__ unsigned lds[256];
    int t = threadIdx.x;
    unsigned s = (t < NCHUNK) ? csum[t] : 0u;
    lds[t] = s; __syncthreads();
    for (int o = 1; o < 256; o <<= 1) {
        unsigned add = (t >= o) ? lds[t - o] : 0u; __syncthreads();
        lds[t] += add; __syncthreads();
    }
    if (t < NCHUNK) cbase[t] = lds[t] - s;
}

__global__ void k_scan3(const unsigned* __restrict__ cnt, const unsigned* __restrict__ cbase,
                        unsigned* __restrict__ off, unsigned* __restrict__ cur,
                        const float* __restrict__ x, float* __restrict__ dinv,
                        float4* __restrict__ xs) {
    int i = blockIdx.x * blockDim.x + threadIdx.x;
    if (i >= NN) return;
    unsigned o = off[i] + cbase[i >> 10];
    off[i] = o; cur[i] = o;
    float d = rsqrtf((float)cnt[i] + 1.0f);
    dinv[i] = d;
    xs[i] = make_float4(x[3*i] * d, x[3*i+1] * d, x[3*i+2] * d, 0.f);
}

template <typename T>
__device__ __forceinline__ void place_loop(const T* __restrict__ ei, long long E,
                                           const unsigned* __restrict__ off,
                                           const unsigned short* __restrict__ r,
                                           unsigned* __restrict__ ridx) {
    long long stride = (long long)gridDim.x * blockDim.x;
    for (long long e = (long long)blockIdx.x * blockDim.x + threadIdx.x; e < E; e += stride) {
        unsigned c = (unsigned)ei[E + e];
        ridx[off[c] + (unsigned)r[e]] = (unsigned)ei[e];
    }
}
__global__ void k_place(const void* ei, long long E, const int* flag,
                        const unsigned* off, const unsigned short* r, unsigned* ridx) {
    if (*flag) place_loop((const long long*)ei, E, off, r, ridx);
    else       place_loop((const int*)ei, E, off, r, ridx);
}

// ---------------- mid path: hist + cursor-place (2 atomic passes) ----------------
template <typename T>
__device__ __forceinline__ void hist_loop(const T* __restrict__ col, long long E,
                                          unsigned* __restrict__ cnt) {
    long long stride = (long long)gridDim.x * blockDim.x;
    for (long long e = (long long)blockIdx.x * blockDim.x + threadIdx.x; e < E; e += stride)
        atomicAdd(&cnt[(unsigned)col[e]], 1u);
}
__global__ void k_histM(const void* ei, long long E, const int* flag, unsigned* cnt) {
    if (*flag) hist_loop(((const long long*)ei) + E, E, cnt);
    else       hist_loop(((const int*)ei) + E, E, cnt);
}
template <typename T>
__device__ __forceinline__ void placeM_loop(const T* __restrict__ ei, long long E,
                                            unsigned* __restrict__ cur, unsigned* __restrict__ ridx) {
    long long stride = (long long)gridDim.x * blockDim.x;
    for (long long e = (long long)blockIdx.x * blockDim.x + threadIdx.x; e < E; e += stride) {
        unsigned c = (unsigned)ei[E + e];
        unsigned pos = atomicAdd(&cur[c], 1u);
        ridx[pos] = (unsigned)ei[e];
    }
}
__global__ void k_placeM(const void* ei, long long E, const int* flag,
                         unsigned* cur, unsigned* ridx) {
    if (*flag) placeM_loop((const long long*)ei, E, cur, ridx);
    else       placeM_loop((const int*)ei, E, cur, ridx);
}

// ---------------- gather layers (no atomics) ----------------
__global__ void k_lay1(const unsigned* __restrict__ off, const unsigned* __restrict__ cnt,
                       const unsigned* __restrict__ ridx, const float4* __restrict__ xs,
                       const float* __restrict__ dinv,
                       const float* __restrict__ W1, const float* __restrict__ b1,
                       const float* __restrict__ W2, float2* __restrict__ hs2) {
    int lane = threadIdx.x & 15;
    int node = blockIdx.x * (blockDim.x >> 4) + (threadIdx.x >> 4);
    if (node >= NN) return;
    unsigned s = off[node], n = cnt[node];
    float a0 = 0.f, a1 = 0.f, a2 = 0.f;
    for (unsigned k = lane; k < n; k += 16) {
        float4 v = xs[ridx[s + k]];
        a0 += v.x; a1 += v.y; a2 += v.z;
    }
#pragma unroll
    for (int m = 8; m; m >>= 1) {
        a0 += __shfl_xor(a0, m); a1 += __shfl_xor(a1, m); a2 += __shfl_xor(a2, m);
    }
    if (lane == 0) {
        float4 sv = xs[node];
        float d = dinv[node];
        float t0 = d*(a0+sv.x), t1 = d*(a1+sv.y), t2 = d*(a2+sv.z);
        float g0 = 0.f, g1 = 0.f;
#pragma unroll
        for (int j = 0; j < 16; ++j) {
            float h = fmaxf(fmaf(t0, W1[j], fmaf(t1, W1[16+j], fmaf(t2, W1[32+j], b1[j]))), 0.f);
            g0 = fmaf(h, W2[2*j],   g0);
            g1 = fmaf(h, W2[2*j+1], g1);
        }
        hs2[node] = make_float2(g0 * d, g1 * d);
    }
}

__global__ void k_lay2(const unsigned* __restrict__ off, const unsigned* __restrict__ cnt,
                       const unsigned* __restrict__ ridx, const float2* __restrict__ hs2,
                       const float* __restrict__ dinv, const float* __restrict__ b2,
                       float2* __restrict__ out) {
    int lane = threadIdx.x & 15;
    int node = blockIdx.x * (blockDim.x >> 4) + (threadIdx.x >> 4);
    if (node >= NN) return;
    unsigned s = off[node], n = cnt[node];
    float a0 = 0.f, a1 = 0.f;
    for (unsigned k = lane; k < n; k += 16) {
        float2 v = hs2[ridx[s + k]];
        a0 += v.x; a1 += v.y;
    }
#pragma unroll
    for (int m = 8; m; m >>= 1) {
        a0 += __shfl_xor(a0, m); a1 += __shfl_xor(a1, m);
    }
    if (lane == 0) {
        float2 sv = hs2[node];
        float d = dinv[node];
        float z0 = d*(a0+sv.x) + b2[0];
        float z1 = d*(a1+sv.y) + b2[1];
        float mx = fmaxf(z0, z1);
        float l  = mx + logf(expf(z0 - mx) + expf(z1 - mx));
        out[node] = make_float2(z0 - l, z1 - l);
    }
}

// ---------------- A/B timing probe: per-XCD local atomics ----------------
template <typename T>
__device__ __forceinline__ void histB_loop(const T* __restrict__ col, long long E,
                                           unsigned* __restrict__ cnt) {
    long long stride = (long long)gridDim.x * blockDim.x;
    for (long long e = (long long)blockIdx.x * blockDim.x + threadIdx.x; e < E; e += stride)
        atom_add_local_u32(&cnt[(unsigned)col[e]], 1u);
}
__global__ void k_histB(const void* ei, long long E, const int* flag, unsigned* cntL) {
    unsigned* c = cntL + (size_t)xcc_id() * NN;
    if (*flag) histB_loop(((const long long*)ei) + E, E, c);
    else       histB_loop(((const int*)ei) + E, E, c);
}

// ---------------- low path (R1 design, known-correct fallback) ----------------
template <typename T>
__device__ __forceinline__ void degL_loop(const T* col, long long E, float* deg) {
    long long stride = (long long)gridDim.x * blockDim.x;
    for (long long e = (long long)blockIdx.x * blockDim.x + threadIdx.x; e < E; e += stride)
        atomicAdd(&deg[(int)col[e]], 1.0f);
}
__global__ void k_degL(const void* ei, long long E, const int* flag, float* deg) {
    if (*flag) degL_loop(((const long long*)ei) + E, E, deg);
    else       degL_loop(((const int*)ei) + E, E, deg);
}
__global__ void k_prepL(const float* __restrict__ x, float* dinv, float4* xs) {
    int i = blockIdx.x * blockDim.x + threadIdx.x;
    if (i >= NN) return;
    float d = rsqrtf(dinv[i] + 1.0f);
    dinv[i] = d;
    xs[i] = make_float4(x[3*i]*d, x[3*i+1]*d, x[3*i+2]*d, 0.f);
}
template <typename T>
__device__ __forceinline__ void sc1L_loop(const T* ei, long long E,
                                          const float4* __restrict__ xs, float4* agg1) {
    long long stride = (long long)gridDim.x * blockDim.x;
    for (long long e = (long long)blockIdx.x * blockDim.x + threadIdx.x; e < E; e += stride) {
        int r = (int)ei[e]; int c = (int)ei[E + e];
        float4 v = xs[r];
        atomicAdd(&agg1[c].x, v.x); atomicAdd(&agg1[c].y, v.y); atomicAdd(&agg1[c].z, v.z);
    }
}
__global__ void k_sc1L(const void* ei, long long E, const int* flag,
                       const float4* __restrict__ xs, float4* agg1) {
    if (*flag) sc1L_loop((const long long*)ei, E, xs, agg1);
    else       sc1L_loop((const int*)ei, E, xs, agg1);
}
__global__ void k_layL(const float* __restrict__ W1, const float* __restrict__ b1,
                       const float* __restrict__ W2, const float* __restrict__ dinv,
                       const float4* __restrict__ xs, const float4* __restrict__ agg1,
                       float2* hs2) {
    int i = blockIdx.x * blockDim.x + threadIdx.x;
    if (i >= NN) return;
    float d = dinv[i]; float4 a = agg1[i]; float4 s = xs[i];
    float t0 = d*(a.x+s.x), t1 = d*(a.y+s.y), t2 = d*(a.z+s.z);
    float g0 = 0.f, g1 = 0.f;
#pragma unroll
    for (int j = 0; j < 16; ++j) {
        float h = fmaxf(t0*W1[j] + t1*W1[16+j] + t2*W1[32+j] + b1[j], 0.f);
        g0 += h*W2[2*j]; g1 += h*W2[2*j+1];
    }
    hs2[i] = make_float2(g0*d, g1*d);
}
template <typename T>
__device__ __forceinline__ void sc2L_loop(const T* ei, long long E,
                                          const float2* __restrict__ hs2, float2* agg2) {
    long long stride = (long long)gridDim.x * blockDim.x;
    for (long long e = (long long)blockIdx.x * blockDim.x + threadIdx.x; e < E; e += stride) {
        int r = (int)ei[e]; int c = (int)ei[E + e];
        float2 v = hs2[r];
        atomicAdd(&agg2[c].x, v.x); atomicAdd(&agg2[c].y, v.y);
    }
}
__global__ void k_sc2L(const void* ei, long long E, const int* flag,
                       const float2* __restrict__ hs2, float2* agg2) {
    if (*flag) sc2L_loop((const long long*)ei, E, hs2, agg2);
    else       sc2L_loop((const int*)ei, E, hs2, agg2);
}
__global__ void k_outL(const float* __restrict__ b2, const float* __restrict__ dinv,
                       const float2* __restrict__ hs2, const float2* __restrict__ agg2,
                       float2* out) {
    int i = blockIdx.x * blockDim.x + threadIdx.x;
    if (i >= NN) return;
    float d = dinv[i]; float2 a = agg2[i]; float2 s = hs2[i];
    float z0 = d*(a.x+s.x) + b2[0];
    float z1 = d*(a.y+s.y) + b2[1];
    float mx = fmaxf(z0, z1);
    float l  = mx + logf(expf(z0 - mx) + expf(z1 - mx));
    out[i] = make_float2(z0 - l, z1 - l);
}

extern "C" void kernel_launch(void* const* d_in, const int* in_sizes, int n_in,
                              void* d_out, int out_size, void* d_ws, size_t ws_size,
                              hipStream_t stream) {
    const float* x  = (const float*)d_in[0];
    const void*  ei = d_in[1];
    const float* W1 = (const float*)d_in[2];
    const float* b1 = (const float*)d_in[3];
    const float* W2 = (const float*)d_in[4];
    const float* b2 = (const float*)d_in[5];
    long long E = (long long)in_sizes[1] / 2;

    char* ws = (char*)d_ws;
    int* flag = (int*)(ws + O_FLAG);
    float2* out = (float2*)d_out;

    int ngrid = (NN + 255) / 256;        // 391 blocks, 1 node/thread
    int lgrid = (NN + 15) / 16;          // 6250 blocks, 16 nodes/block (16 lanes/node)
    long long eg = (E + 255) / 256;
    int egrid = (int)(eg > 4096 ? 4096 : eg);

    k_detect<<<1, 64, 0, stream>>>(ei, flag);

    if (ws_size >= SZ_FULL) {
        unsigned*       cnt   = (unsigned*)(ws + O_CNT);
        unsigned*       off   = (unsigned*)(ws + O_OFF);
        unsigned*       cur   = (unsigned*)(ws + O_CUR);
        float*          dinv  = (float*)(ws + O_DINV);
        unsigned*       csum  = (unsigned*)(ws + O_CSUM);
        unsigned*       cbase = (unsigned*)(ws + O_CBASE);
        float4*         xs    = (float4*)(ws + O_XS);
        float2*         hs2   = (float2*)(ws + O_HS2);
        unsigned*       ridx  = (unsigned*)(ws + O_RIDX);
        unsigned short* r     = (unsigned short*)(ws + O_R);
        bool ab = (ws_size >= SZ_FULL_AB);
        unsigned* cntL = (unsigned*)(ws + O_CNTL);

        k_zero <<<98, 256, 0, stream>>>((float4*)(ws + O_CNT), 25000);
        if (ab) k_zero<<<782, 256, 0, stream>>>((float4*)(ws + O_CNTL), 200000);
        k_rank <<<egrid, 256, 0, stream>>>(ei, E, flag, cnt, r);
        k_scan1<<<NCHUNK, 256, 0, stream>>>(cnt, off, csum);
        k_scan2<<<1, 256, 0, stream>>>(csum, cbase);
        k_scan3<<<ngrid, 256, 0, stream>>>(cnt, cbase, off, cur, x, dinv, xs);
        k_place<<<egrid, 256, 0, stream>>>(ei, E, flag, off, r, ridx);
        k_lay1 <<<lgrid, 256, 0, stream>>>(off, cnt, ridx, xs, dinv, W1, b1, W2, hs2);
        k_lay2 <<<lgrid, 256, 0, stream>>>(off, cnt, ridx, hs2, dinv, b2, out);
        if (ab) k_histB<<<egrid, 256, 0, stream>>>(ei, E, flag, cntL);
    } else if (ws_size >= SZ_MID) {
        unsigned* cnt   = (unsigned*)(ws + O_CNT);
        unsigned* off   = (unsigned*)(ws + O_OFF);
        unsigned* cur   = (unsigned*)(ws + O_CUR);
        float*    dinv  = (float*)(ws + O_DINV);
        unsigned* csum  = (unsigned*)(ws + O_CSUM);
        unsigned* cbase = (unsigned*)(ws + O_CBASE);
        float4*   xs    = (float4*)(ws + O_XS);
        float2*   hs2   = (float2*)(ws + O_HS2);
        unsigned* ridx  = (unsigned*)(ws + O_RIDX);

        k_zero  <<<98, 256, 0, stream>>>((float4*)(ws + O_CNT), 25000);
        k_histM <<<egrid, 256, 0, stream>>>(ei, E, flag, cnt);
        k_scan1 <<<NCHUNK, 256, 0, stream>>>(cnt, off, csum);
        k_scan2 <<<1, 256, 0, stream>>>(csum, cbase);
        k_scan3 <<<ngrid, 256, 0, stream>>>(cnt, cbase, off, cur, x, dinv, xs);
        k_placeM<<<egrid, 256, 0, stream>>>(ei, E, flag, cur, ridx);
        k_lay1  <<<lgrid, 256, 0, stream>>>(off, cnt, ridx, xs, dinv, W1, b1, W2, hs2);
        k_lay2  <<<lgrid, 256, 0, stream>>>(off, cnt, ridx, hs2, dinv, b2, out);
    } else {
        float*  dinv = (float*)(ws + L_DINV);
        float4* xs   = (float4*)(ws + L_XS);
        float2* hs2  = (float2*)(ws + L_HS2);
        float4* agg1 = (float4*)(ws + L_AGG1);
        float2* agg2 = (float2*)(ws + L_AGG2);

        k_zero <<<98, 256, 0, stream>>>((float4*)(ws + L_DINV), 25000);
        k_zero <<<150, 256, 0, stream>>>((float4*)(ws + L_AGG1), 150000);
        k_degL <<<egrid, 256, 0, stream>>>(ei, E, flag, dinv);
        k_prepL<<<ngrid, 256, 0, stream>>>(x, dinv, xs);
        k_sc1L <<<egrid, 256, 0, stream>>>(ei, E, flag, xs, agg1);
        k_layL <<<ngrid, 256, 0, stream>>>(W1, b1, W2, dinv, xs, agg1, hs2);
        k_sc2L <<<egrid, 256, 0, stream>>>(ei, E, flag, hs2, agg2);
        k_outL <<<ngrid, 256, 0, stream>>>(b2, dinv, hs2, agg2, out);
    }
}